// Round 3
// baseline (356.556 us; speedup 1.0000x reference)
//
#include <hip/hip_runtime.h>
#include <hip/hip_bf16.h>
#include <math.h>

#define H_DIM 4096
#define N_EXP 64
#define N_TOK 16384
#define KB    128      // k-chunk staged in LDS (floats)
#define NE    8        // experts per wave
#define NWAVE 4
#define TB    64       // tokens per block (= lanes per wave)
#define EB    32       // experts per block (NWAVE * NE)

// ---- logits GEMM: lane = token, wave = 64 tokens x 8 experts ----
// x: staged in LDS (coalesced global loads), read 1x ds_read_b128/jg with
//    xor swizzle (col ^= row&7) -> bandwidth-floor, no conflicts.
// W: wave-uniform global reads (expert id uniform) -> SMEM/L1 pipe, 0 DS.
__global__ __launch_bounds__(256)
void router_logits_kernel(const float* __restrict__ x,
                          const float* __restrict__ W,
                          const float* __restrict__ bias,
                          float* __restrict__ logits) {
    __shared__ float4 xlds[TB * (KB / 4)];    // 64*32 float4 = 32 KB
    __shared__ float  olds[TB * (EB + 1)];    // 64*33 = 8.25 KB

    const int tid  = threadIdx.x;
    const int lane = tid & 63;                               // token row
    const int wid  = __builtin_amdgcn_readfirstlane(tid >> 6);
    const int tok0 = (blockIdx.x >> 1) * TB;
    const int eb   = (blockIdx.x & 1) * EB;
    const int ew   = eb + wid * NE;                          // wave's expert base

    const float4* W4 = (const float4*)W;                     // row stride H_DIM/4

    float acc[NE];
#pragma unroll
    for (int i = 0; i < NE; ++i) acc[i] = 0.0f;

    for (int kc = 0; kc < H_DIM; kc += KB) {
        __syncthreads();
        // stage x[tok0..tok0+64)[kc..kc+KB), coalesced, xor-swizzled
#pragma unroll
        for (int i = 0; i < TB * (KB / 4) / 256; ++i) {      // 8 iters
            int idx = i * 256 + tid;
            int row = idx >> 5, col = idx & 31;
            float4 v = *(const float4*)(x + (size_t)(tok0 + row) * H_DIM + kc + col * 4);
            xlds[row * 32 + (col ^ (row & 7))] = v;
        }
        __syncthreads();

        const int kg = kc >> 2;
#pragma unroll 2
        for (int jg = 0; jg < KB / 4; ++jg) {
            float4 xv = xlds[lane * 32 + (jg ^ (lane & 7))];
            float4 wf[NE];
#pragma unroll
            for (int i = 0; i < NE; ++i)
                wf[i] = W4[(size_t)(ew + i) * (H_DIM / 4) + kg + jg];
#pragma unroll
            for (int i = 0; i < NE; ++i) {
                acc[i] = fmaf(wf[i].x, xv.x, acc[i]);
                acc[i] = fmaf(wf[i].y, xv.y, acc[i]);
                acc[i] = fmaf(wf[i].z, xv.z, acc[i]);
                acc[i] = fmaf(wf[i].w, xv.w, acc[i]);
            }
        }
    }

#pragma unroll
    for (int i = 0; i < NE; ++i) acc[i] += bias[ew + i];

    // transpose through LDS for coalesced logits store
#pragma unroll
    for (int i = 0; i < NE; ++i)
        olds[lane * (EB + 1) + wid * NE + i] = acc[i];       // bank=(lane+e)%32: clean
    __syncthreads();
#pragma unroll
    for (int i = 0; i < TB * EB / 256; ++i) {                // 8 iters
        int idx = i * 256 + tid;
        int row = idx >> 5, col = idx & 31;
        logits[(size_t)(tok0 + row) * N_EXP + eb + col] = olds[row * (EB + 1) + col];
    }
}

// ---------------- softmax + top-2 + renorm weights ----------------
__global__ __launch_bounds__(256)
void topk_kernel(const float* __restrict__ logits,
                 float* __restrict__ wout,
                 float* __restrict__ iout) {
    int n = blockIdx.x * 256 + threadIdx.x;
    if (n >= N_TOK) return;

    float l[64];
    const float4* lp = (const float4*)(logits + (size_t)n * N_EXP);
#pragma unroll
    for (int i = 0; i < 16; ++i) {
        float4 v = lp[i];
        l[4 * i + 0] = v.x; l[4 * i + 1] = v.y;
        l[4 * i + 2] = v.z; l[4 * i + 3] = v.w;
    }

    float v1 = -INFINITY, v2 = -INFINITY;
    int   i1 = 0, i2 = 0;
#pragma unroll
    for (int i = 0; i < 64; ++i) {
        float li = l[i];
        if (li > v1)      { v2 = v1; i2 = i1; v1 = li; i1 = i; }
        else if (li > v2) { v2 = li; i2 = i; }
    }

    float Z = 0.0f;
#pragma unroll
    for (int i = 0; i < 64; ++i) Z += expf(l[i] - v1);

    float p1 = 1.0f / Z;
    float p2 = expf(v2 - v1) / Z;

    float t  = expf(p2 - p1);
    float w0 = 1.0f / (1.0f + t);
    float w1 = t / (1.0f + t);

    wout[2 * n + 0] = w0;
    wout[2 * n + 1] = w1;
    iout[2 * n + 0] = (float)i1;
    iout[2 * n + 1] = (float)i2;
}

// ---------------- expert mask [E][K][N] as 0.0/1.0 floats ----------------
__global__ __launch_bounds__(256)
void mask_kernel(const float* __restrict__ iout,
                 float* __restrict__ mask) {
    int gid = blockIdx.x * 256 + threadIdx.x;
    int n   = gid & (N_TOK - 1);
    int ek  = gid >> 14;                            // e*2 + k
    float idxf = iout[(size_t)n * 2 + (ek & 1)];
    mask[gid] = (idxf == (float)(ek >> 1)) ? 1.0f : 0.0f;
}

extern "C" void kernel_launch(void* const* d_in, const int* in_sizes, int n_in,
                              void* d_out, int out_size, void* d_ws, size_t ws_size,
                              hipStream_t stream) {
    const float* x  = (const float*)d_in[0];
    const float* W  = (const float*)d_in[1];
    const float* b  = (const float*)d_in[2];

    float* out    = (float*)d_out;
    float* logits = out;                          // N_TOK * 64
    float* wout   = logits + (size_t)N_TOK * 64;  // N_TOK * 2
    float* iout   = wout   + (size_t)N_TOK * 2;   // N_TOK * 2
    float* mask   = iout   + (size_t)N_TOK * 2;   // 64 * 2 * N_TOK

    router_logits_kernel<<<(N_TOK / TB) * 2, 256, 0, stream>>>(x, W, b, logits);
    topk_kernel<<<N_TOK / 256, 256, 0, stream>>>(logits, wout, iout);
    mask_kernel<<<(N_EXP * 2 * N_TOK) / 256, 256, 0, stream>>>(iout, mask);
}

// Round 5
// 206.084 us; speedup vs baseline: 1.7302x; 1.7302x over previous
//
#include <hip/hip_runtime.h>
#include <hip/hip_bf16.h>
#include <math.h>

#define H_DIM 4096
#define N_EXP 64
#define N_TOK 16384
#define BM    32
#define KB    64
#define NCHUNK (H_DIM / KB)   // 64
#define MARGIN 1e-3f

typedef __attribute__((ext_vector_type(8))) short short8v;
typedef __attribute__((ext_vector_type(4))) float float4v;

__device__ __forceinline__ unsigned short bf16_rn(float f) {
    unsigned u = __builtin_bit_cast(unsigned, f);
    u += 0x7FFFu + ((u >> 16) & 1u);
    return (unsigned short)(u >> 16);
}
__device__ __forceinline__ float bf16_hi_f32(unsigned u) {
    return __builtin_bit_cast(float, u & 0xFFFF0000u);
}
__device__ __forceinline__ void gload_lds16(const void* g, void* l) {
    __builtin_amdgcn_global_load_lds(
        (const __attribute__((address_space(1))) unsigned int*)g,
        (__attribute__((address_space(3))) unsigned int*)l, 16, 0, 0);
}

// ---- W split: w = wh(trunc) + wm(rn) + wl(rn); also zero the fixup counter ----
__global__ __launch_bounds__(256)
void wconvert_kernel(const float* __restrict__ W,
                     unsigned short* __restrict__ wh,
                     unsigned short* __restrict__ wm,
                     unsigned short* __restrict__ wl,
                     int* __restrict__ counter) {
    int i = blockIdx.x * 256 + threadIdx.x;
    if (i == 0) *counter = 0;
    float w = W[i];
    unsigned u = __builtin_bit_cast(unsigned, w);
    wh[i] = (unsigned short)(u >> 16);
    float r1 = w - bf16_hi_f32(u);
    unsigned short m = bf16_rn(r1);
    wm[i] = m;
    float r2 = r1 - bf16_hi_f32((unsigned)m << 16);
    wl[i] = bf16_rn(r2);
}

// ---- logits via 6-term split-bf16 MFMA: hh, mh, hm, mm, lh, h*wl ----
__global__ __launch_bounds__(256, 2)
void router_mfma_kernel(const float* __restrict__ x,
                        const unsigned short* __restrict__ wh,
                        const unsigned short* __restrict__ wm,
                        const unsigned short* __restrict__ wl,
                        const float* __restrict__ bias,
                        float* __restrict__ logits) {
    // per buffer (float4 units): [0,512) x | [512,1024) wh | [1024,1536) wm | [1536,2048) wl
    __shared__ float4 lds[2][2048];   // 64 KB

    const int tid  = threadIdx.x;
    const int lane = tid & 63;
    const int wid  = __builtin_amdgcn_readfirstlane(tid >> 6);
    const int tok0 = blockIdx.x * BM;

    const int q    = lane >> 4;
    const int e15  = lane & 15;
    const int m0   = (wid & 1) * 16;
    const int n0   = (wid >> 1) * 32;
    const int arow = m0 + e15;
    const int r15  = arow & 15;
    const int e0   = n0 + e15;
    const int e1   = n0 + 16 + e15;

    float4v acc0 = {0.f, 0.f, 0.f, 0.f};
    float4v acc1 = {0.f, 0.f, 0.f, 0.f};

    auto stage = [&](int cb, int kc) {
        // x: 512 units, pre-swizzled source (u4 ^= row&15), dest linear
#pragma unroll
        for (int i = 0; i < 2; ++i) {
            int uph = i * 256 + tid;
            int row = uph >> 4, up = uph & 15;
            int u4  = up ^ (row & 15);
            const float* src = x + (size_t)(tok0 + row) * H_DIM + kc + u4 * 4;
            void* dst = (char*)&lds[cb][0] + (size_t)(i * 256 + wid * 64) * 16;
            gload_lds16(src, dst);
        }
        // W terms (bf16): 3*512 units, source kg ^= e&7, dest linear
#pragma unroll
        for (int i = 0; i < 6; ++i) {
            int uw = i * 256 + tid;
            int z  = uw & 511;
            int e  = z >> 3, kgp = z & 7;
            int kg = kgp ^ (e & 7);
            const unsigned short* wsrc = (i < 2) ? wh : (i < 4) ? wm : wl;
            const unsigned short* src  = wsrc + (size_t)e * H_DIM + kc + kg * 8;
            void* dst = (char*)&lds[cb][512] + (size_t)(i * 256 + wid * 64) * 16;
            gload_lds16(src, dst);
        }
    };

    auto compute = [&](int cb) {
        const char* bufc = (const char*)&lds[cb][0];
#pragma unroll
        for (int t = 0; t < 2; ++t) {
            float f[8];
#pragma unroll
            for (int h = 0; h < 2; ++h) {
                int u4 = (t * 8 + q * 2 + h) ^ r15;
                float4 a = *(const float4*)(bufc + (size_t)(arow * 16 + u4) * 16);
                f[h * 4 + 0] = a.x; f[h * 4 + 1] = a.y;
                f[h * 4 + 2] = a.z; f[h * 4 + 3] = a.w;
            }
            short8v ah, am, al;
#pragma unroll
            for (int j = 0; j < 8; ++j) {
                unsigned u = __builtin_bit_cast(unsigned, f[j]);
                ah[j] = (short)(u >> 16);
                float r1 = f[j] - bf16_hi_f32(u);
                unsigned u1 = __builtin_bit_cast(unsigned, r1);
                am[j] = (short)(u1 >> 16);
                float r2 = r1 - bf16_hi_f32(u1);
                al[j] = (short)bf16_rn(r2);
            }
            int kq   = t * 4 + q;
            int kgp0 = kq ^ (e0 & 7);
            int kgp1 = kq ^ (e1 & 7);
            short8v bh0 = *(const short8v*)(bufc + 512 * 16  + (size_t)(e0 * 8 + kgp0) * 16);
            short8v bh1 = *(const short8v*)(bufc + 512 * 16  + (size_t)(e1 * 8 + kgp1) * 16);
            short8v bm0 = *(const short8v*)(bufc + 1024 * 16 + (size_t)(e0 * 8 + kgp0) * 16);
            short8v bm1 = *(const short8v*)(bufc + 1024 * 16 + (size_t)(e1 * 8 + kgp1) * 16);
            short8v bl0 = *(const short8v*)(bufc + 1536 * 16 + (size_t)(e0 * 8 + kgp0) * 16);
            short8v bl1 = *(const short8v*)(bufc + 1536 * 16 + (size_t)(e1 * 8 + kgp1) * 16);

            acc0 = __builtin_amdgcn_mfma_f32_16x16x32_bf16(ah, bh0, acc0, 0, 0, 0);
            acc1 = __builtin_amdgcn_mfma_f32_16x16x32_bf16(ah, bh1, acc1, 0, 0, 0);
            acc0 = __builtin_amdgcn_mfma_f32_16x16x32_bf16(am, bh0, acc0, 0, 0, 0);
            acc1 = __builtin_amdgcn_mfma_f32_16x16x32_bf16(am, bh1, acc1, 0, 0, 0);
            acc0 = __builtin_amdgcn_mfma_f32_16x16x32_bf16(ah, bm0, acc0, 0, 0, 0);
            acc1 = __builtin_amdgcn_mfma_f32_16x16x32_bf16(ah, bm1, acc1, 0, 0, 0);
            acc0 = __builtin_amdgcn_mfma_f32_16x16x32_bf16(am, bm0, acc0, 0, 0, 0);
            acc1 = __builtin_amdgcn_mfma_f32_16x16x32_bf16(am, bm1, acc1, 0, 0, 0);
            acc0 = __builtin_amdgcn_mfma_f32_16x16x32_bf16(al, bh0, acc0, 0, 0, 0);
            acc1 = __builtin_amdgcn_mfma_f32_16x16x32_bf16(al, bh1, acc1, 0, 0, 0);
            acc0 = __builtin_amdgcn_mfma_f32_16x16x32_bf16(ah, bl0, acc0, 0, 0, 0);
            acc1 = __builtin_amdgcn_mfma_f32_16x16x32_bf16(ah, bl1, acc1, 0, 0, 0);
        }
    };

    stage(0, 0);
    for (int c = 0; c < NCHUNK; ++c) {
        __builtin_amdgcn_s_barrier();                    // prev compute done, buf free
        if (c + 1 < NCHUNK) {
            stage((c + 1) & 1, (c + 1) * KB);
            asm volatile("s_waitcnt vmcnt(8)" ::: "memory");   // chunk c landed
        } else {
            asm volatile("s_waitcnt vmcnt(0)" ::: "memory");
        }
        __builtin_amdgcn_s_barrier();                    // all waves see buf[c&1]
        compute(c & 1);
    }

    float bv0 = bias[e0], bv1 = bias[e1];
#pragma unroll
    for (int r = 0; r < 4; ++r) {
        int token = tok0 + m0 + q * 4 + r;               // C: row=(lane>>4)*4+r, col=lane&15
        logits[(size_t)token * N_EXP + e0] = acc0[r] + bv0;
        logits[(size_t)token * N_EXP + e1] = acc1[r] + bv1;
    }
}

// ---- fallback exact-f32 GEMM (round-2 kernel) ----
__global__ __launch_bounds__(256)
void router_logits_f32(const float* __restrict__ x,
                       const float* __restrict__ W,
                       const float* __restrict__ bias,
                       float* __restrict__ logits) {
    __shared__ float4 wlds[32 * 64];
    __shared__ float4 xlds[32][32];
    const int tid = threadIdx.x;
    const int lane = tid & 63;
    const int wid = __builtin_amdgcn_readfirstlane(tid >> 6);
    const int tok0b = blockIdx.x * 32;
    const int trow0 = wid * 8;
    float acc[8];
#pragma unroll
    for (int t = 0; t < 8; ++t) acc[t] = 0.0f;
    for (int kc = 0; kc < H_DIM; kc += 128) {
        __syncthreads();
#pragma unroll
        for (int i = 0; i < 8; ++i) {
            int idx = tid + i * 256;
            int se = idx >> 5, sj = idx & 31;
            float4 v = *(const float4*)(W + (size_t)se * H_DIM + kc + sj * 4);
            wlds[sj * 64 + (se ^ (sj & 7))] = v;
        }
#pragma unroll
        for (int i = 0; i < 4; ++i) {
            int idx = tid + i * 256;
            int row = idx >> 5, col = idx & 31;
            xlds[row][col] = *(const float4*)(x + (size_t)(tok0b + row) * H_DIM + kc + col * 4);
        }
        __syncthreads();
#pragma unroll 4
        for (int jg = 0; jg < 32; ++jg) {
            float4 w = wlds[jg * 64 + (lane ^ (jg & 7))];
#pragma unroll
            for (int t = 0; t < 8; ++t) {
                float4 xv = xlds[trow0 + t][jg];
                acc[t] = fmaf(w.x, xv.x, acc[t]);
                acc[t] = fmaf(w.y, xv.y, acc[t]);
                acc[t] = fmaf(w.z, xv.z, acc[t]);
                acc[t] = fmaf(w.w, xv.w, acc[t]);
            }
        }
    }
    float bv = bias[lane];
#pragma unroll
    for (int t = 0; t < 8; ++t)
        logits[(size_t)(tok0b + trow0 + t) * N_EXP + lane] = acc[t] + bv;
}

// ---- softmax + top-2 + renorm; flag near-ties for exact fixup ----
template <int FIX>
__global__ __launch_bounds__(256)
void topk_kernel(const float* __restrict__ logits,
                 float* __restrict__ wout,
                 float* __restrict__ iout,
                 int* __restrict__ counter,
                 int* __restrict__ list) {
    int n = blockIdx.x * 256 + threadIdx.x;
    if (n >= N_TOK) return;
    float l[64];
    const float4* lp = (const float4*)(logits + (size_t)n * N_EXP);
#pragma unroll
    for (int i = 0; i < 16; ++i) {
        float4 v = lp[i];
        l[4 * i + 0] = v.x; l[4 * i + 1] = v.y;
        l[4 * i + 2] = v.z; l[4 * i + 3] = v.w;
    }
    float v1 = -INFINITY, v2 = -INFINITY, v3 = -INFINITY;
    int i1 = 0, i2 = 0;
#pragma unroll
    for (int i = 0; i < 64; ++i) {
        float li = l[i];
        if (li > v1)      { v3 = v2; v2 = v1; i2 = i1; v1 = li; i1 = i; }
        else if (li > v2) { v3 = v2; v2 = li; i2 = i; }
        else if (li > v3) { v3 = li; }
    }
    float Z = 0.0f;
#pragma unroll
    for (int i = 0; i < 64; ++i) Z += expf(l[i] - v1);
    float p1 = 1.0f / Z;
    float p2 = expf(v2 - v1) / Z;
    float t  = expf(p2 - p1);
    wout[2 * n + 0] = 1.0f / (1.0f + t);
    wout[2 * n + 1] = t / (1.0f + t);
    iout[2 * n + 0] = (float)i1;
    iout[2 * n + 1] = (float)i2;
    if (FIX) {
        if ((v1 - v2 < MARGIN) || (v2 - v3 < MARGIN)) {
            int s = atomicAdd(counter, 1);
            list[s] = n;
        }
    }
}

// ---- exact-f32 recompute of flagged tokens; overwrite weights/idx ----
__global__ __launch_bounds__(256)
void fixup_kernel(const float* __restrict__ x,
                  const float* __restrict__ W,
                  const float* __restrict__ bias,
                  float* __restrict__ wout,
                  float* __restrict__ iout,
                  const int* __restrict__ counter,
                  const int* __restrict__ list) {
    __shared__ float plds[4][64];
    __shared__ float llds[64];
    int cnt = counter[0];
    if (cnt > N_TOK) cnt = N_TOK;
    const int e = threadIdx.x & 63;
    const int s = threadIdx.x >> 6;
    for (int it = blockIdx.x; it < cnt; it += 64) {
        int n = list[it];
        const float4* xr = (const float4*)(x + (size_t)n * H_DIM) + s * 256;
        const float4* wr = (const float4*)(W + (size_t)e * H_DIM) + s * 256;
        float p = 0.f;
        for (int j = 0; j < 256; ++j) {
            float4 a = xr[j], w = wr[j];
            p = fmaf(a.x, w.x, p); p = fmaf(a.y, w.y, p);
            p = fmaf(a.z, w.z, p); p = fmaf(a.w, w.w, p);
        }
        plds[s][e] = p;
        __syncthreads();
        if (threadIdx.x < 64)
            llds[e] = ((plds[0][e] + plds[1][e]) + (plds[2][e] + plds[3][e])) + bias[e];
        __syncthreads();
        if (threadIdx.x == 0) {
            float v1 = -INFINITY, v2 = -INFINITY;
            int i1 = 0, i2 = 0;
            for (int i = 0; i < 64; ++i) {
                float li = llds[i];
                if (li > v1)      { v2 = v1; i2 = i1; v1 = li; i1 = i; }
                else if (li > v2) { v2 = li; i2 = i; }
            }
            float Z = 0.0f;
            for (int i = 0; i < 64; ++i) Z += expf(llds[i] - v1);
            float p1 = 1.0f / Z;
            float p2 = expf(v2 - v1) / Z;
            float t  = expf(p2 - p1);
            wout[2 * n + 0] = 1.0f / (1.0f + t);
            wout[2 * n + 1] = t / (1.0f + t);
            iout[2 * n + 0] = (float)i1;
            iout[2 * n + 1] = (float)i2;
        }
        __syncthreads();
    }
}

// ---- expert mask [E][K][N] ----
__global__ __launch_bounds__(256)
void mask_kernel(const float* __restrict__ iout,
                 float* __restrict__ mask) {
    int gid = blockIdx.x * 256 + threadIdx.x;
    int n   = gid & (N_TOK - 1);
    int ek  = gid >> 14;
    float idxf = iout[(size_t)n * 2 + (ek & 1)];
    mask[gid] = (idxf == (float)(ek >> 1)) ? 1.0f : 0.0f;
}

extern "C" void kernel_launch(void* const* d_in, const int* in_sizes, int n_in,
                              void* d_out, int out_size, void* d_ws, size_t ws_size,
                              hipStream_t stream) {
    const float* x  = (const float*)d_in[0];
    const float* W  = (const float*)d_in[1];
    const float* b  = (const float*)d_in[2];

    float* out    = (float*)d_out;
    float* logits = out;
    float* wout   = logits + (size_t)N_TOK * 64;
    float* iout   = wout   + (size_t)N_TOK * 2;
    float* mask   = iout   + (size_t)N_TOK * 2;

    const size_t wsplit = (size_t)N_EXP * H_DIM;                       // 262144
    const size_t need   = 3 * wsplit * sizeof(unsigned short) + 4 + (size_t)N_TOK * 4;
    if (ws_size >= need) {
        unsigned short* wh = (unsigned short*)d_ws;
        unsigned short* wm = wh + wsplit;
        unsigned short* wl = wm + wsplit;
        int* counter = (int*)((char*)d_ws + 3 * wsplit * sizeof(unsigned short));
        int* list    = counter + 1;
        wconvert_kernel<<<(int)(wsplit / 256), 256, 0, stream>>>(W, wh, wm, wl, counter);
        router_mfma_kernel<<<N_TOK / BM, 256, 0, stream>>>(x, wh, wm, wl, b, logits);
        topk_kernel<1><<<N_TOK / 256, 256, 0, stream>>>(logits, wout, iout, counter, list);
        fixup_kernel<<<64, 256, 0, stream>>>(x, W, b, wout, iout, counter, list);
    } else {
        router_logits_f32<<<N_TOK / 32, 256, 0, stream>>>(x, W, b, logits);
        topk_kernel<0><<<N_TOK / 256, 256, 0, stream>>>(logits, wout, iout, nullptr, nullptr);
    }
    mask_kernel<<<(N_EXP * 2 * N_TOK) / 256, 256, 0, stream>>>(iout, mask);
}